// Round 1
// baseline (664.529 us; speedup 1.0000x reference)
//
#include <hip/hip_runtime.h>

#define T_SEQ   4096
#define DM      1024
#define NB      4
#define ROWS    (NB * T_SEQ)   /* 16384 */

typedef unsigned short ushort_t;

typedef __attribute__((ext_vector_type(8))) short bf16x8;
typedef __attribute__((ext_vector_type(4))) float f32x4;

__device__ __forceinline__ float bf2f(ushort_t u) {
  return __uint_as_float(((unsigned int)u) << 16);
}
__device__ __forceinline__ ushort_t f2bf(float f) {
  unsigned int u = __float_as_uint(f);
  u += 0x7FFFu + ((u >> 16) & 1u);
  return (ushort_t)(u >> 16);
}

__device__ __forceinline__ void async16(const void* g, void* l) {
  __builtin_amdgcn_global_load_lds(
      (const __attribute__((address_space(1))) unsigned int*)g,
      (__attribute__((address_space(3))) unsigned int*)l, 16, 0, 0);
}

// ---------------- f32 -> bf16 conversion (vectorized, grid-stride) ----------
__global__ __launch_bounds__(256)
void cvt_bf16(const float* __restrict__ in, ushort_t* __restrict__ out, const int n4) {
  const int stride = gridDim.x * blockDim.x;
  for (int i = blockIdx.x * blockDim.x + threadIdx.x; i < n4; i += stride) {
    const float4 f = ((const float4*)in)[i];
    ushort4 o;
    o.x = f2bf(f.x); o.y = f2bf(f.y); o.z = f2bf(f.z); o.w = f2bf(f.w);
    ((ushort4*)out)[i] = o;
  }
}

// ---------------- GEMM: C = A(bf16) @ W(bf16)^T + bias -----------------------
// A: [M][K] row-major bf16, W: [N][K] row-major bf16 (so B[k][n] = W[n][k]).
// 128x128 tile, BK=32, 256 threads (4 waves, 2x2 of 64x64), mfma 16x16x32 bf16.
__device__ __forceinline__ void store_out(ushort_t* C, size_t i, float v) { C[i] = f2bf(v); }
__device__ __forceinline__ void store_out(float*    C, size_t i, float v) { C[i] = v; }

template <typename OutT>
__global__ __launch_bounds__(256, 2)
void gemm_bt(const ushort_t* __restrict__ A, const ushort_t* __restrict__ W,
             const float* __restrict__ bias, OutT* __restrict__ C,
             const int M, const int N, const int K) {
  __shared__ ushort_t As[128 * 32];
  __shared__ ushort_t Bs[128 * 32];
  const int ntn  = N >> 7;
  const int tm   = (int)blockIdx.x / ntn;
  const int tn   = (int)blockIdx.x % ntn;
  const int m0   = tm << 7, n0 = tn << 7;
  const int tid  = threadIdx.x;
  const int lane = tid & 63;
  const int wave = tid >> 6;
  const int wr   = (wave >> 1) * 64;  // wave row offset in tile
  const int wc   = (wave & 1) * 64;   // wave col offset in tile
  // staging coords: thread covers 16B = 8 bf16; row = tid/4, k-slot = tid%4
  const int srow  = tid >> 2;
  const int skoff = (tid & 3) * 8;
  const size_t a_base = (size_t)(m0 + srow) * K + skoff;
  const size_t b_base = (size_t)(n0 + srow) * K + skoff;
  ushort_t* as_dst = &As[srow * 32 + skoff];
  ushort_t* bs_dst = &Bs[srow * 32 + skoff];
  const int kq   = (lane >> 4) * 8;   // k offset within BK for this lane
  const int rsel = lane & 15;

  f32x4 acc[4][4];
  #pragma unroll
  for (int i = 0; i < 4; ++i)
    #pragma unroll
    for (int j = 0; j < 4; ++j)
      acc[i][j] = (f32x4){0.f, 0.f, 0.f, 0.f};

  for (int kt = 0; kt < K; kt += 32) {
    async16(&A[a_base + kt],                   as_dst);
    async16(&A[a_base + (size_t)64 * K + kt],  as_dst + 64 * 32);
    async16(&W[b_base + kt],                   bs_dst);
    async16(&W[b_base + (size_t)64 * K + kt],  bs_dst + 64 * 32);
    __syncthreads();  // compiler drains vmcnt before barrier

    bf16x8 af[4], bfr[4];
    #pragma unroll
    for (int f = 0; f < 4; ++f) {
      af[f]  = *(const bf16x8*)&As[(wr + f * 16 + rsel) * 32 + kq];
      bfr[f] = *(const bf16x8*)&Bs[(wc + f * 16 + rsel) * 32 + kq];
    }
    #pragma unroll
    for (int fm = 0; fm < 4; ++fm)
      #pragma unroll
      for (int fn = 0; fn < 4; ++fn)
        acc[fm][fn] = __builtin_amdgcn_mfma_f32_16x16x32_bf16(af[fm], bfr[fn], acc[fm][fn], 0, 0, 0);
    __syncthreads();
  }

  // epilogue: C/D layout col = lane&15, row = (lane>>4)*4 + reg  [verified m89]
  #pragma unroll
  for (int fn = 0; fn < 4; ++fn) {
    const int col = n0 + wc + fn * 16 + rsel;
    const float bvv = bias[col];
    #pragma unroll
    for (int fm = 0; fm < 4; ++fm) {
      const int row0 = m0 + wr + fm * 16 + (lane >> 4) * 4;
      #pragma unroll
      for (int r = 0; r < 4; ++r)
        store_out(C, (size_t)(row0 + r) * N + col, acc[fm][fn][r] + bvv);
    }
  }
}

// ---------------- WKV scan ---------------------------------------------------
// One lane per channel (b, d). 64 blocks x 64 threads. head h = group g since
// HEAD_DIM == 64. Register double-buffered prefetch of 8 timesteps.
__device__ __forceinline__ void scan_load(const ushort_t* __restrict__ kp,
                                          const ushort_t* __restrict__ vp,
                                          const ushort_t* __restrict__ rp,
                                          size_t base, int t0,
                                          ushort_t (&K_)[8], ushort_t (&V_)[8], ushort_t (&R_)[8]) {
  #pragma unroll
  for (int u = 0; u < 8; ++u) {
    const size_t idx = base + (size_t)(t0 + u) * DM;
    K_[u] = kp[idx];
    V_[u] = vp[idx];
    R_[u] = rp[idx];
  }
}

__device__ __forceinline__ void scan_compute(ushort_t* __restrict__ G,
                                             size_t base, int t0,
                                             const ushort_t (&K_)[8], const ushort_t (&V_)[8],
                                             const ushort_t (&R_)[8],
                                             float df, float eb, float& num, float& den) {
  #pragma unroll
  for (int u = 0; u < 8; ++u) {
    float kf = bf2f(K_[u]);
    kf = fminf(fmaxf(kf, -10.f), 10.f);
    const float ek = __expf(kf);
    const float bw = eb * ek;
    const float vv = bf2f(V_[u]);
    const float rr = bf2f(R_[u]);
    const float numer = fmaf(bw, vv, num);
    const float denom = den + bw + 1e-6f;
    const float wkv = numer * __builtin_amdgcn_rcpf(denom);
    const float sig = __builtin_amdgcn_rcpf(1.f + __expf(-rr));
    G[base + (size_t)(t0 + u) * DM] = f2bf(sig * wkv);
    num = fmaf(num, df, ek * vv);
    den = fmaf(den, df, ek);
  }
}

__global__ __launch_bounds__(64, 4)
void wkv_scan(const ushort_t* __restrict__ kp, const ushort_t* __restrict__ vp,
              const ushort_t* __restrict__ rp, const float* __restrict__ decay,
              const float* __restrict__ bonus, ushort_t* __restrict__ G) {
  const int b    = blockIdx.x >> 4;
  const int g    = blockIdx.x & 15;
  const int lane = threadIdx.x;
  const int ch   = g * 64 + lane;               // also (h, dh) index: h = g, dh = lane
  const float df = __expf(-__expf(decay[ch]));
  const float eb = __expf(bonus[ch]);
  const size_t base = (size_t)b * T_SEQ * DM + ch;
  float num = 0.f, den = 0.f;

  ushort_t ka[8], va[8], ra[8];
  ushort_t kb2[8], vb2[8], rb2[8];

  scan_load(kp, vp, rp, base, 0, ka, va, ra);
  for (int tb = 0; tb < T_SEQ; tb += 16) {
    scan_load(kp, vp, rp, base, tb + 8, kb2, vb2, rb2);
    scan_compute(G, base, tb, ka, va, ra, df, eb, num, den);
    if (tb + 16 < T_SEQ)
      scan_load(kp, vp, rp, base, tb + 16, ka, va, ra);
    scan_compute(G, base, tb + 8, kb2, vb2, rb2, df, eb, num, den);
  }
}

// ---------------- launch -----------------------------------------------------
extern "C" void kernel_launch(void* const* d_in, const int* in_sizes, int n_in,
                              void* d_out, int out_size, void* d_ws, size_t ws_size,
                              hipStream_t stream) {
  const float* q   = (const float*)d_in[0];
  const float* ky  = (const float*)d_in[1];
  const float* vl  = (const float*)d_in[2];
  const float* Wr  = (const float*)d_in[3];
  const float* br  = (const float*)d_in[4];
  const float* Wk  = (const float*)d_in[5];
  const float* bk  = (const float*)d_in[6];
  const float* Wv  = (const float*)d_in[7];
  const float* bv  = (const float*)d_in[8];
  const float* Wo  = (const float*)d_in[9];
  const float* bo  = (const float*)d_in[10];
  const float* decay = (const float*)d_in[11];
  const float* bonus = (const float*)d_in[12];
  float* out = (float*)d_out;

  const size_t NE = (size_t)ROWS * DM;   // 16,777,216 elements
  const size_t WE = (size_t)DM * DM;     // 1,048,576

  ushort_t* xb = (ushort_t*)d_ws;        // staging X (bf16), later aliased as G
  ushort_t* wb = xb + NE;                // staging W (bf16)
  ushort_t* rp = wb + WE;
  ushort_t* kp = rp + NE;
  ushort_t* vp = kp + NE;
  ushort_t* G  = xb;                     // alias: xb no longer needed at scan time

  const int big4 = (int)(NE / 4);
  const int w4   = (int)(WE / 4);
  dim3 cB(256);
  dim3 gBig(2048), gW(1024);
  dim3 gemmGrid((ROWS / 128) * (DM / 128)), gemmBlk(256);

  // r projection
  cvt_bf16<<<gBig, cB, 0, stream>>>(q, xb, big4);
  cvt_bf16<<<gW,   cB, 0, stream>>>(Wr, wb, w4);
  gemm_bt<ushort_t><<<gemmGrid, gemmBlk, 0, stream>>>(xb, wb, br, rp, ROWS, DM, DM);
  // k projection
  cvt_bf16<<<gBig, cB, 0, stream>>>(ky, xb, big4);
  cvt_bf16<<<gW,   cB, 0, stream>>>(Wk, wb, w4);
  gemm_bt<ushort_t><<<gemmGrid, gemmBlk, 0, stream>>>(xb, wb, bk, kp, ROWS, DM, DM);
  // v projection
  cvt_bf16<<<gBig, cB, 0, stream>>>(vl, xb, big4);
  cvt_bf16<<<gW,   cB, 0, stream>>>(Wv, wb, w4);
  gemm_bt<ushort_t><<<gemmGrid, gemmBlk, 0, stream>>>(xb, wb, bv, vp, ROWS, DM, DM);
  // WKV scan + gate -> G (bf16)
  wkv_scan<<<dim3(64), dim3(64), 0, stream>>>(kp, vp, rp, decay, bonus, G);
  // output projection (f32 out)
  cvt_bf16<<<gW,   cB, 0, stream>>>(Wo, wb, w4);
  gemm_bt<float><<<gemmGrid, gemmBlk, 0, stream>>>(G, wb, bo, out, ROWS, DM, DM);
}

// Round 2
// 321.201 us; speedup vs baseline: 2.0689x; 2.0689x over previous
//
#include <hip/hip_runtime.h>

#define T_SEQ   4096
#define DM      1024
#define NB      4
#define ROWS    (NB * T_SEQ)   /* 16384 */
#define NCH     64             /* chunks over time */
#define LCH     (T_SEQ / NCH)  /* 64 steps per chunk */

typedef unsigned short ushort_t;

typedef __attribute__((ext_vector_type(8))) short bf16x8;
typedef __attribute__((ext_vector_type(4))) float f32x4;

__device__ __forceinline__ float bf2f(ushort_t u) {
  return __uint_as_float(((unsigned int)u) << 16);
}
__device__ __forceinline__ ushort_t f2bf(float f) {
  unsigned int u = __float_as_uint(f);
  u += 0x7FFFu + ((u >> 16) & 1u);
  return (ushort_t)(u >> 16);
}

__device__ __forceinline__ void async16(const void* g, void* l) {
  __builtin_amdgcn_global_load_lds(
      (const __attribute__((address_space(1))) unsigned int*)g,
      (__attribute__((address_space(3))) unsigned int*)l, 16, 0, 0);
}

// ---------------- f32 -> bf16 conversion (vectorized, grid-stride) ----------
__global__ __launch_bounds__(256)
void cvt_bf16(const float* __restrict__ in, ushort_t* __restrict__ out, const int n4) {
  const int stride = gridDim.x * blockDim.x;
  for (int i = blockIdx.x * blockDim.x + threadIdx.x; i < n4; i += stride) {
    const float4 f = ((const float4*)in)[i];
    ushort4 o;
    o.x = f2bf(f.x); o.y = f2bf(f.y); o.z = f2bf(f.z); o.w = f2bf(f.w);
    ((ushort4*)out)[i] = o;
  }
}

// ---------------- GEMM: C = A(bf16) @ W(bf16)^T + bias -----------------------
__device__ __forceinline__ void store_out(ushort_t* C, size_t i, float v) { C[i] = f2bf(v); }
__device__ __forceinline__ void store_out(float*    C, size_t i, float v) { C[i] = v; }

template <typename OutT>
__global__ __launch_bounds__(256, 2)
void gemm_bt(const ushort_t* __restrict__ A, const ushort_t* __restrict__ W,
             const float* __restrict__ bias, OutT* __restrict__ C,
             const int M, const int N, const int K) {
  __shared__ ushort_t As[128 * 32];
  __shared__ ushort_t Bs[128 * 32];
  const int ntn  = N >> 7;
  const int tm   = (int)blockIdx.x / ntn;
  const int tn   = (int)blockIdx.x % ntn;
  const int m0   = tm << 7, n0 = tn << 7;
  const int tid  = threadIdx.x;
  const int lane = tid & 63;
  const int wave = tid >> 6;
  const int wr   = (wave >> 1) * 64;
  const int wc   = (wave & 1) * 64;
  const int srow  = tid >> 2;
  const int skoff = (tid & 3) * 8;
  const size_t a_base = (size_t)(m0 + srow) * K + skoff;
  const size_t b_base = (size_t)(n0 + srow) * K + skoff;
  ushort_t* as_dst = &As[srow * 32 + skoff];
  ushort_t* bs_dst = &Bs[srow * 32 + skoff];
  const int kq   = (lane >> 4) * 8;
  const int rsel = lane & 15;

  f32x4 acc[4][4];
  #pragma unroll
  for (int i = 0; i < 4; ++i)
    #pragma unroll
    for (int j = 0; j < 4; ++j)
      acc[i][j] = (f32x4){0.f, 0.f, 0.f, 0.f};

  for (int kt = 0; kt < K; kt += 32) {
    async16(&A[a_base + kt],                   as_dst);
    async16(&A[a_base + (size_t)64 * K + kt],  as_dst + 64 * 32);
    async16(&W[b_base + kt],                   bs_dst);
    async16(&W[b_base + (size_t)64 * K + kt],  bs_dst + 64 * 32);
    __syncthreads();

    bf16x8 af[4], bfr[4];
    #pragma unroll
    for (int f = 0; f < 4; ++f) {
      af[f]  = *(const bf16x8*)&As[(wr + f * 16 + rsel) * 32 + kq];
      bfr[f] = *(const bf16x8*)&Bs[(wc + f * 16 + rsel) * 32 + kq];
    }
    #pragma unroll
    for (int fm = 0; fm < 4; ++fm)
      #pragma unroll
      for (int fn = 0; fn < 4; ++fn)
        acc[fm][fn] = __builtin_amdgcn_mfma_f32_16x16x32_bf16(af[fm], bfr[fn], acc[fm][fn], 0, 0, 0);
    __syncthreads();
  }

  #pragma unroll
  for (int fn = 0; fn < 4; ++fn) {
    const int col = n0 + wc + fn * 16 + rsel;
    const float bvv = bias[col];
    #pragma unroll
    for (int fm = 0; fm < 4; ++fm) {
      const int row0 = m0 + wr + fm * 16 + (lane >> 4) * 4;
      #pragma unroll
      for (int r = 0; r < 4; ++r)
        store_out(C, (size_t)(row0 + r) * N + col, acc[fm][fn][r] + bvv);
    }
  }
}

// ---------------- WKV chunked scan ------------------------------------------
// Linear recurrence num_t = df*num_{t-1} + ek_t*v_t (same den). Chunk the time
// axis: pass1 computes per-chunk local sums (zero init), pass2 does the tiny
// exclusive scan across chunks, pass3 replays each chunk with the true carry
// and emits the gated output G = sigmoid(r) * wkv.

// Pass 1: grid = B * NCH * (DM/256), block = 256. One thread per (b,chunk,ch).
__global__ __launch_bounds__(256)
void wkv_pass1(const ushort_t* __restrict__ kp, const ushort_t* __restrict__ vp,
               const float* __restrict__ decay,
               float* __restrict__ s_num, float* __restrict__ s_den) {
  const int tid = threadIdx.x;
  const int grp = blockIdx.x & 3;            // DM/256 groups
  const int c   = (blockIdx.x >> 2) & (NCH - 1);
  const int b   = (int)blockIdx.x >> 8;      // 4*64 blocks per batch
  const int ch  = grp * 256 + tid;
  const float df = __expf(-__expf(decay[ch]));
  size_t idx = (size_t)b * T_SEQ * DM + (size_t)(c * LCH) * DM + ch;
  float num = 0.f, den = 0.f;
  for (int u = 0; u < LCH; ++u, idx += DM) {
    float kf = bf2f(kp[idx]);
    kf = fminf(fmaxf(kf, -10.f), 10.f);
    const float ek = __expf(kf);
    const float vv = bf2f(vp[idx]);
    num = fmaf(num, df, ek * vv);
    den = fmaf(den, df, ek);
  }
  const size_t si = ((size_t)b * NCH + c) * DM + ch;
  s_num[si] = num;
  s_den[si] = den;
}

// Pass 2: exclusive scan across chunks. grid = B*DM/256, block = 256.
__global__ __launch_bounds__(256)
void wkv_pass2(const float* __restrict__ decay,
               float* __restrict__ s_num, float* __restrict__ s_den) {
  const int tid = threadIdx.x;
  const int grp = blockIdx.x & 3;
  const int b   = (int)blockIdx.x >> 2;
  const int ch  = grp * 256 + tid;
  const float dfL = __expf(-__expf(decay[ch]) * (float)LCH);
  float an = 0.f, ad = 0.f;
  size_t si = (size_t)b * NCH * DM + ch;
  for (int c = 0; c < NCH; ++c, si += DM) {
    const float ln = s_num[si], ld = s_den[si];
    s_num[si] = an; s_den[si] = ad;          // exclusive prefix (carry into chunk c)
    an = fmaf(an, dfL, ln);
    ad = fmaf(ad, dfL, ld);
  }
}

// Pass 3: replay each chunk with true carry, emit G. Same grid as pass1.
__global__ __launch_bounds__(256)
void wkv_pass3(const ushort_t* __restrict__ kp, const ushort_t* __restrict__ vp,
               const ushort_t* __restrict__ rp, const float* __restrict__ decay,
               const float* __restrict__ bonus,
               const float* __restrict__ s_num, const float* __restrict__ s_den,
               ushort_t* __restrict__ G) {
  const int tid = threadIdx.x;
  const int grp = blockIdx.x & 3;
  const int c   = (blockIdx.x >> 2) & (NCH - 1);
  const int b   = (int)blockIdx.x >> 8;
  const int ch  = grp * 256 + tid;
  const float df = __expf(-__expf(decay[ch]));
  const float eb = __expf(bonus[ch]);
  const size_t si = ((size_t)b * NCH + c) * DM + ch;
  float num = s_num[si], den = s_den[si];
  size_t idx = (size_t)b * T_SEQ * DM + (size_t)(c * LCH) * DM + ch;
  for (int u = 0; u < LCH; ++u, idx += DM) {
    float kf = bf2f(kp[idx]);
    kf = fminf(fmaxf(kf, -10.f), 10.f);
    const float ek = __expf(kf);
    const float bw = eb * ek;
    const float vv = bf2f(vp[idx]);
    const float rr = bf2f(rp[idx]);
    const float numer = fmaf(bw, vv, num);
    const float denom = den + bw + 1e-6f;
    const float wkv = numer * __builtin_amdgcn_rcpf(denom);
    const float sig = __builtin_amdgcn_rcpf(1.f + __expf(-rr));
    G[idx] = f2bf(sig * wkv);
    num = fmaf(num, df, ek * vv);
    den = fmaf(den, df, ek);
  }
}

// ---------------- launch -----------------------------------------------------
extern "C" void kernel_launch(void* const* d_in, const int* in_sizes, int n_in,
                              void* d_out, int out_size, void* d_ws, size_t ws_size,
                              hipStream_t stream) {
  const float* q   = (const float*)d_in[0];
  const float* ky  = (const float*)d_in[1];
  const float* vl  = (const float*)d_in[2];
  const float* Wr  = (const float*)d_in[3];
  const float* br  = (const float*)d_in[4];
  const float* Wk  = (const float*)d_in[5];
  const float* bk  = (const float*)d_in[6];
  const float* Wv  = (const float*)d_in[7];
  const float* bv  = (const float*)d_in[8];
  const float* Wo  = (const float*)d_in[9];
  const float* bo  = (const float*)d_in[10];
  const float* decay = (const float*)d_in[11];
  const float* bonus = (const float*)d_in[12];
  float* out = (float*)d_out;

  const size_t NE = (size_t)ROWS * DM;   // 16,777,216 elements
  const size_t WE = (size_t)DM * DM;     // 1,048,576

  ushort_t* xb = (ushort_t*)d_ws;        // staging X (bf16), later aliased as G
  ushort_t* wb = xb + NE;                // staging W (bf16); aliased by scan summaries
  ushort_t* rp = wb + WE;
  ushort_t* kp = rp + NE;
  ushort_t* vp = kp + NE;
  ushort_t* G  = xb;                     // alias: xb free at scan time
  // chunk summaries alias wb (2 MB): B*NCH*DM floats each = 1 MB each
  float* s_num = (float*)wb;
  float* s_den = s_num + (size_t)NB * NCH * DM;

  const int big4 = (int)(NE / 4);
  const int w4   = (int)(WE / 4);
  dim3 cB(256);
  dim3 gBig(2048), gW(1024);
  dim3 gemmGrid((ROWS / 128) * (DM / 128)), gemmBlk(256);
  dim3 scanGrid(NB * NCH * (DM / 256)), scanBlk(256);

  // r projection
  cvt_bf16<<<gBig, cB, 0, stream>>>(q, xb, big4);
  cvt_bf16<<<gW,   cB, 0, stream>>>(Wr, wb, w4);
  gemm_bt<ushort_t><<<gemmGrid, gemmBlk, 0, stream>>>(xb, wb, br, rp, ROWS, DM, DM);
  // k projection
  cvt_bf16<<<gBig, cB, 0, stream>>>(ky, xb, big4);
  cvt_bf16<<<gW,   cB, 0, stream>>>(Wk, wb, w4);
  gemm_bt<ushort_t><<<gemmGrid, gemmBlk, 0, stream>>>(xb, wb, bk, kp, ROWS, DM, DM);
  // v projection
  cvt_bf16<<<gBig, cB, 0, stream>>>(vl, xb, big4);
  cvt_bf16<<<gW,   cB, 0, stream>>>(Wv, wb, w4);
  gemm_bt<ushort_t><<<gemmGrid, gemmBlk, 0, stream>>>(xb, wb, bv, vp, ROWS, DM, DM);
  // WKV chunk-parallel scan + gate -> G (bf16). Summaries alias wb (free now).
  wkv_pass1<<<scanGrid, scanBlk, 0, stream>>>(kp, vp, decay, s_num, s_den);
  wkv_pass2<<<dim3(NB * DM / 256), scanBlk, 0, stream>>>(decay, s_num, s_den);
  wkv_pass3<<<scanGrid, scanBlk, 0, stream>>>(kp, vp, rp, decay, bonus, s_num, s_den, G);
  // output projection (f32 out); Wo cvt overwrites wb AFTER pass3 consumed it
  cvt_bf16<<<gW,   cB, 0, stream>>>(Wo, wb, w4);
  gemm_bt<float><<<gemmGrid, gemmBlk, 0, stream>>>(G, wb, bo, out, ROWS, DM, DM);
}

// Round 3
// 275.563 us; speedup vs baseline: 2.4115x; 1.1656x over previous
//
#include <hip/hip_runtime.h>

#define T_SEQ   4096
#define DM      1024
#define NB      4
#define ROWS    (NB * T_SEQ)   /* 16384 */
#define NCH     64             /* chunks over time */
#define LCH     (T_SEQ / NCH)  /* 64 steps per chunk */

typedef unsigned short ushort_t;

typedef __attribute__((ext_vector_type(8))) short bf16x8;
typedef __attribute__((ext_vector_type(4))) float f32x4;

__device__ __forceinline__ float bf2f(ushort_t u) {
  return __uint_as_float(((unsigned int)u) << 16);
}
__device__ __forceinline__ ushort_t f2bf(float f) {
  unsigned int u = __float_as_uint(f);
  u += 0x7FFFu + ((u >> 16) & 1u);
  return (ushort_t)(u >> 16);
}

__device__ __forceinline__ void async16(const void* g, void* l) {
  __builtin_amdgcn_global_load_lds(
      (const __attribute__((address_space(1))) unsigned int*)g,
      (__attribute__((address_space(3))) unsigned int*)l, 16, 0, 0);
}

// st_16x32 swizzled byte offset of element (row, col) in a 256x64 bf16 tile.
// Subtile = 16 rows x 32 cols (1024 B); XOR byte-bit5 with bit9 (== row bit 3).
__device__ __forceinline__ int fragoff(int row, int col) {
  int p = (((row >> 4) * 2 + (col >> 5)) << 10) + ((row & 15) << 6) + ((col & 31) << 1);
  return p ^ (((row >> 3) & 1) << 5);
}

// ---------------- f32 -> bf16 conversion (vectorized, grid-stride) ----------
__global__ __launch_bounds__(256)
void cvt_bf16(const float* __restrict__ in, ushort_t* __restrict__ out, const int n4) {
  const int stride = gridDim.x * blockDim.x;
  for (int i = blockIdx.x * blockDim.x + threadIdx.x; i < n4; i += stride) {
    const float4 f = ((const float4*)in)[i];
    ushort4 o;
    o.x = f2bf(f.x); o.y = f2bf(f.y); o.z = f2bf(f.z); o.w = f2bf(f.w);
    ((ushort4*)out)[i] = o;
  }
}

__device__ __forceinline__ void store_out(ushort_t* C, size_t i, float v) { C[i] = f2bf(v); }
__device__ __forceinline__ void store_out(float*    C, size_t i, float v) { C[i] = v; }

// ---------------- GEMM 256x256 8-phase: C = A(bf16) @ W(bf16)^T + bias -------
// A: [M][K] bf16 row-major, W: [N][K] bf16 row-major. 512 thr = 8 waves (2Mx4N),
// per-wave 128x64 out. BK=64, dbuf LDS 128 KiB, st_16x32 swizzle, counted vmcnt.
template <typename OutT>
__global__ __launch_bounds__(512, 2)
void gemm256(const ushort_t* __restrict__ A, const ushort_t* __restrict__ W,
             const float* __restrict__ bias, OutT* __restrict__ C,
             const int M, const int N, const int K) {
  __shared__ char smem[131072];   // A: 2x32KB @0, B: 2x32KB @65536
  const int T = K >> 6;
  const int nwg = (M >> 8) * (N >> 8);
  const int wg  = ((int)blockIdx.x & 7) * (nwg >> 3) + ((int)blockIdx.x >> 3); // XCD chunked (nwg%8==0)
  const int ntn = N >> 8;
  const int tm = wg / ntn, tn = wg % ntn;
  const int m0 = tm << 8, n0 = tn << 8;
  const int tid  = threadIdx.x;
  const int lane = tid & 63;
  const int wave = tid >> 6;
  const int wm128 = (wave >> 2) * 128;
  const int wn64  = (wave & 3) * 64;
  const int r15 = lane & 15;
  const int kq8 = (lane >> 4) * 8;

  // staging: thread t writes 16B at linear LDS byte rho*8192 + t*16 within a
  // 16KB half-tile; source element = unswizzle of that position.
  int srow[2], scol[2];
  #pragma unroll
  for (int rho = 0; rho < 2; ++rho) {
    int p  = rho * 8192 + tid * 16;
    int pp = p ^ (((p >> 9) & 1) << 5);
    int e  = pp >> 1;
    int S = e >> 9, inr = e & 511;
    srow[rho] = ((S >> 1) << 4) + (inr >> 5);   // 0..127 within half
    scol[rho] = ((S & 1) << 5) + (inr & 31);    // 0..63
  }

  auto stageA = [&](int tile, int half) {
    const int boff = ((tile & 1) << 15) + (half << 14);
    #pragma unroll
    for (int rho = 0; rho < 2; ++rho) {
      const ushort_t* g = A + (size_t)(m0 + half * 128 + srow[rho]) * K + (tile << 6) + scol[rho];
      async16(g, &smem[boff + rho * 8192 + tid * 16]);
    }
  };
  auto stageB = [&](int tile, int half) {
    const int boff = 65536 + ((tile & 1) << 15) + (half << 14);
    #pragma unroll
    for (int rho = 0; rho < 2; ++rho) {
      const ushort_t* g = W + (size_t)(n0 + half * 128 + srow[rho]) * K + (tile << 6) + scol[rho];
      async16(g, &smem[boff + rho * 8192 + tid * 16]);
    }
  };

  f32x4 acc[8][4];
  #pragma unroll
  for (int i = 0; i < 8; ++i)
    #pragma unroll
    for (int j = 0; j < 4; ++j)
      acc[i][j] = (f32x4){0.f, 0.f, 0.f, 0.f};
  bf16x8 bf[4][2];

  // prologue: tile0 A+B, tile1 B. vmcnt(4) -> tile0 complete, B(1) in flight.
  stageA(0, 0); stageA(0, 1); stageB(0, 0); stageB(0, 1); stageB(1, 0); stageB(1, 1);
  asm volatile("s_waitcnt vmcnt(4)" ::: "memory");
  __builtin_amdgcn_s_barrier();

  // per phase Q: reads (A quadrant; B all at Q0), stage, barrier, MFMA, barrier
#define GPHASE(Q, STG, TAILW)                                                    \
  {                                                                              \
    bf16x8 af[2][2];                                                             \
    _Pragma("unroll") for (int fl = 0; fl < 2; ++fl)                             \
      _Pragma("unroll") for (int ks = 0; ks < 2; ++ks)                           \
        af[fl][ks] = *(const bf16x8*)&smem[abase +                               \
            fragoff(wm128 + ((2 * (Q) + fl) << 4) + r15, (ks << 5) + kq8)];      \
    if ((Q) == 0) {                                                              \
      _Pragma("unroll") for (int fj = 0; fj < 4; ++fj)                           \
        _Pragma("unroll") for (int ks = 0; ks < 2; ++ks)                         \
          bf[fj][ks] = *(const bf16x8*)&smem[bbase +                             \
              fragoff(wn64 + (fj << 4) + r15, (ks << 5) + kq8)];                 \
    }                                                                            \
    STG();                                                                       \
    __builtin_amdgcn_s_barrier();                                                \
    __builtin_amdgcn_s_setprio(1);                                               \
    _Pragma("unroll") for (int fl = 0; fl < 2; ++fl)                             \
      _Pragma("unroll") for (int fj = 0; fj < 4; ++fj)                           \
        _Pragma("unroll") for (int ks = 0; ks < 2; ++ks)                         \
          acc[2 * (Q) + fl][fj] = __builtin_amdgcn_mfma_f32_16x16x32_bf16(       \
              af[fl][ks], bf[fj][ks], acc[2 * (Q) + fl][fj], 0, 0, 0);           \
    __builtin_amdgcn_s_setprio(0);                                               \
    TAILW();                                                                     \
    __builtin_amdgcn_s_barrier();                                                \
  }

  for (int j = 0; j < T; ++j) {
    const int abase = (j & 1) << 15;
    const int bbase = 65536 + ((j & 1) << 15);
    const bool p1 = (j + 1 < T), p2 = (j + 2 < T);
    auto stA0 = [&] { if (p1) stageA(j + 1, 0); };
    auto stA1 = [&] { if (p1) stageA(j + 1, 1); };
    auto stB0 = [&] { if (p2) stageB(j + 2, 0); };
    auto stB1 = [&] { if (p2) stageB(j + 2, 1); };
    auto nw   = [&] {};
    auto bwait = [&] {
      if (p2) asm volatile("s_waitcnt vmcnt(4)" ::: "memory");
      else    asm volatile("s_waitcnt vmcnt(0)" ::: "memory");
    };
    GPHASE(0, stA0, nw);
    GPHASE(1, stA1, nw);
    GPHASE(2, stB0, nw);
    GPHASE(3, stB1, bwait);
  }
#undef GPHASE

  // epilogue: C/D layout col = lane&15, row = (lane>>4)*4 + reg
  float bias4[4];
  #pragma unroll
  for (int fj = 0; fj < 4; ++fj) bias4[fj] = bias[n0 + wn64 + fj * 16 + r15];
  #pragma unroll
  for (int fi = 0; fi < 8; ++fi) {
    const int row0 = m0 + wm128 + fi * 16 + (lane >> 4) * 4;
    #pragma unroll
    for (int fj = 0; fj < 4; ++fj) {
      const int col = n0 + wn64 + fj * 16 + r15;
      #pragma unroll
      for (int r = 0; r < 4; ++r)
        store_out(C, (size_t)(row0 + r) * N + col, acc[fi][fj][r] + bias4[fj]);
    }
  }
}

// ---------------- WKV chunked scan ------------------------------------------
__global__ __launch_bounds__(256)
void wkv_pass1(const ushort_t* __restrict__ kp, const ushort_t* __restrict__ vp,
               const float* __restrict__ decay,
               float* __restrict__ s_num, float* __restrict__ s_den) {
  const int tid = threadIdx.x;
  const int grp = blockIdx.x & 3;
  const int c   = (blockIdx.x >> 2) & (NCH - 1);
  const int b   = (int)blockIdx.x >> 8;
  const int ch  = grp * 256 + tid;
  const float df = __expf(-__expf(decay[ch]));
  size_t idx = (size_t)b * T_SEQ * DM + (size_t)(c * LCH) * DM + ch;
  float num = 0.f, den = 0.f;
  for (int u = 0; u < LCH; ++u, idx += DM) {
    float kf = bf2f(kp[idx]);
    kf = fminf(fmaxf(kf, -10.f), 10.f);
    const float ek = __expf(kf);
    const float vv = bf2f(vp[idx]);
    num = fmaf(num, df, ek * vv);
    den = fmaf(den, df, ek);
  }
  const size_t si = ((size_t)b * NCH + c) * DM + ch;
  s_num[si] = num;
  s_den[si] = den;
}

__global__ __launch_bounds__(256)
void wkv_pass2(const float* __restrict__ decay,
               float* __restrict__ s_num, float* __restrict__ s_den) {
  const int tid = threadIdx.x;
  const int grp = blockIdx.x & 3;
  const int b   = (int)blockIdx.x >> 2;
  const int ch  = grp * 256 + tid;
  const float dfL = __expf(-__expf(decay[ch]) * (float)LCH);
  float an = 0.f, ad = 0.f;
  size_t si = (size_t)b * NCH * DM + ch;
  for (int c = 0; c < NCH; ++c, si += DM) {
    const float ln = s_num[si], ld = s_den[si];
    s_num[si] = an; s_den[si] = ad;
    an = fmaf(an, dfL, ln);
    ad = fmaf(ad, dfL, ld);
  }
}

__global__ __launch_bounds__(256)
void wkv_pass3(const ushort_t* __restrict__ kp, const ushort_t* __restrict__ vp,
               const ushort_t* __restrict__ rp, const float* __restrict__ decay,
               const float* __restrict__ bonus,
               const float* __restrict__ s_num, const float* __restrict__ s_den,
               ushort_t* __restrict__ G) {
  const int tid = threadIdx.x;
  const int grp = blockIdx.x & 3;
  const int c   = (blockIdx.x >> 2) & (NCH - 1);
  const int b   = (int)blockIdx.x >> 8;
  const int ch  = grp * 256 + tid;
  const float df = __expf(-__expf(decay[ch]));
  const float eb = __expf(bonus[ch]);
  const size_t si = ((size_t)b * NCH + c) * DM + ch;
  float num = s_num[si], den = s_den[si];
  size_t idx = (size_t)b * T_SEQ * DM + (size_t)(c * LCH) * DM + ch;
  for (int u = 0; u < LCH; ++u, idx += DM) {
    float kf = bf2f(kp[idx]);
    kf = fminf(fmaxf(kf, -10.f), 10.f);
    const float ek = __expf(kf);
    const float bw = eb * ek;
    const float vv = bf2f(vp[idx]);
    const float rr = bf2f(rp[idx]);
    const float numer = fmaf(bw, vv, num);
    const float denom = den + bw + 1e-6f;
    const float wkv = numer * __builtin_amdgcn_rcpf(denom);
    const float sig = __builtin_amdgcn_rcpf(1.f + __expf(-rr));
    G[idx] = f2bf(sig * wkv);
    num = fmaf(num, df, ek * vv);
    den = fmaf(den, df, ek);
  }
}

// ---------------- launch -----------------------------------------------------
extern "C" void kernel_launch(void* const* d_in, const int* in_sizes, int n_in,
                              void* d_out, int out_size, void* d_ws, size_t ws_size,
                              hipStream_t stream) {
  const float* q   = (const float*)d_in[0];
  const float* ky  = (const float*)d_in[1];
  const float* vl  = (const float*)d_in[2];
  const float* Wr  = (const float*)d_in[3];
  const float* br  = (const float*)d_in[4];
  const float* Wk  = (const float*)d_in[5];
  const float* bk  = (const float*)d_in[6];
  const float* Wv  = (const float*)d_in[7];
  const float* bv  = (const float*)d_in[8];
  const float* Wo  = (const float*)d_in[9];
  const float* bo  = (const float*)d_in[10];
  const float* decay = (const float*)d_in[11];
  const float* bonus = (const float*)d_in[12];
  float* out = (float*)d_out;

  const size_t NE = (size_t)ROWS * DM;
  const size_t WE = (size_t)DM * DM;

  ushort_t* xb = (ushort_t*)d_ws;
  ushort_t* wb = xb + NE;
  ushort_t* rp = wb + WE;
  ushort_t* kp = rp + NE;
  ushort_t* vp = kp + NE;
  ushort_t* G  = xb;
  float* s_num = (float*)wb;
  float* s_den = s_num + (size_t)NB * NCH * DM;

  const int big4 = (int)(NE / 4);
  const int w4   = (int)(WE / 4);
  dim3 cB(256);
  dim3 gBig(2048), gW(1024);
  dim3 gemmGrid((ROWS / 256) * (DM / 256)), gemmBlk(512);
  dim3 scanGrid(NB * NCH * (DM / 256)), scanBlk(256);

  // r projection
  cvt_bf16<<<gBig, cB, 0, stream>>>(q, xb, big4);
  cvt_bf16<<<gW,   cB, 0, stream>>>(Wr, wb, w4);
  gemm256<ushort_t><<<gemmGrid, gemmBlk, 0, stream>>>(xb, wb, br, rp, ROWS, DM, DM);
  // k projection
  cvt_bf16<<<gBig, cB, 0, stream>>>(ky, xb, big4);
  cvt_bf16<<<gW,   cB, 0, stream>>>(Wk, wb, w4);
  gemm256<ushort_t><<<gemmGrid, gemmBlk, 0, stream>>>(xb, wb, bk, kp, ROWS, DM, DM);
  // v projection
  cvt_bf16<<<gBig, cB, 0, stream>>>(vl, xb, big4);
  cvt_bf16<<<gW,   cB, 0, stream>>>(Wv, wb, w4);
  gemm256<ushort_t><<<gemmGrid, gemmBlk, 0, stream>>>(xb, wb, bv, vp, ROWS, DM, DM);
  // WKV chunk-parallel scan + gate -> G (bf16)
  wkv_pass1<<<scanGrid, scanBlk, 0, stream>>>(kp, vp, decay, s_num, s_den);
  wkv_pass2<<<dim3(NB * DM / 256), scanBlk, 0, stream>>>(decay, s_num, s_den);
  wkv_pass3<<<scanGrid, scanBlk, 0, stream>>>(kp, vp, rp, decay, bonus, s_num, s_den, G);
  // output projection (f32 out)
  cvt_bf16<<<gW,   cB, 0, stream>>>(Wo, wb, w4);
  gemm256<float><<<gemmGrid, gemmBlk, 0, stream>>>(G, wb, bo, out, ROWS, DM, DM);
}